// Round 1
// baseline (267.627 us; speedup 1.0000x reference)
//
#include <hip/hip_runtime.h>
#include <math.h>

#define DD 96
#define VOX (96*96*96)
#define NB 8
#define NC 128
#define L3 125

// ---------------- alpha: per-batch sigmoid of double contraction -----------
__global__ void alpha_kernel(const float* __restrict__ enc,
                             const float* __restrict__ c1_w,
                             const float* __restrict__ c1_b,
                             const float* __restrict__ f1_w,
                             const float* __restrict__ f1_b,
                             float* __restrict__ alpha) {
    int b = blockIdx.x;
    int t = threadIdx.x;
    const float* e = enc + (size_t)b * NC * L3;
    float s = 0.f;
    for (int i = t; i < NC * L3; i += blockDim.x) {
        int c = i / L3;
        int v = i - c * L3;
        s += e[i] * c1_w[c] * f1_w[v];
    }
    // wave64 reduce then cross-wave via LDS
    for (int off = 32; off > 0; off >>= 1) s += __shfl_down(s, off, 64);
    __shared__ float red[4];
    int lane = t & 63, wid = t >> 6;
    if (lane == 0) red[wid] = s;
    __syncthreads();
    if (t == 0) {
        float tot = 0.f;
        for (int w = 0; w < (int)(blockDim.x >> 6); ++w) tot += red[w];
        float fwsum = 0.f;
        #pragma unroll 5
        for (int v = 0; v < L3; ++v) fwsum += f1_w[v];
        float x = tot + c1_b[0] * fwsum + f1_b[0];
        alpha[b] = 1.f / (1.f + expf(-x));   // ALPHA_M = 1
    }
}

// ---------------- separable 7-tap box blur (zero padded) -------------------
// axis pass: sums 7 neighbors along the given stride; out = raw sum
__global__ void blur_axis(const float* __restrict__ in, float* __restrict__ out,
                          int stride) {
    int idx = blockIdx.x * blockDim.x + threadIdx.x;
    if (idx >= 3 * VOX) return;
    int voxel = idx % VOX;
    int p;
    if (stride == DD * DD)      p = voxel / (DD * DD);
    else if (stride == DD)      p = (voxel / DD) % DD;
    else                        p = voxel % DD;
    float s = 0.f;
    #pragma unroll
    for (int j = -3; j <= 3; ++j) {
        int q = p + j;
        if (q >= 0 && q < DD) s += in[idx + j * stride];
    }
    out[idx] = s;
}

// final x pass: sum, /343, clip to ±0.01, scale by 96 (D=H=W)
__global__ void blur_x_final(const float* __restrict__ in, float* __restrict__ out) {
    int idx = blockIdx.x * blockDim.x + threadIdx.x;
    if (idx >= 3 * VOX) return;
    int p = idx % DD;
    float s = 0.f;
    #pragma unroll
    for (int j = -3; j <= 3; ++j) {
        int q = p + j;
        if (q >= 0 && q < DD) s += in[idx + j];
    }
    float v = s * (1.0f / 343.0f);
    v = fminf(fmaxf(v, -0.01f), 0.01f);
    out[idx] = v * 96.0f;   // fold in scale = [D,H,W] = 96
}

// ---------------- trilinear sampling of orig + mask ------------------------
__global__ void sample_kernel(const float* __restrict__ orig,
                              const float* __restrict__ mask,
                              const float* __restrict__ field,   // scaled disp per unit alpha
                              const float* __restrict__ alpha,
                              float* __restrict__ out) {
    int idx = blockIdx.x * blockDim.x + threadIdx.x;
    if (idx >= NB * VOX) return;
    int b = idx / VOX;
    int voxel = idx - b * VOX;
    int z = voxel / (DD * DD);
    int y = (voxel / DD) % DD;
    int x = voxel % DD;

    float a = alpha[b];
    float cz = (float)z + a * field[voxel];
    float cy = (float)y + a * field[VOX + voxel];
    float cx = (float)x + a * field[2 * VOX + voxel];
    cz = fminf(fmaxf(cz, 0.f), (float)(DD - 1));
    cy = fminf(fmaxf(cy, 0.f), (float)(DD - 1));
    cx = fminf(fmaxf(cx, 0.f), (float)(DD - 1));

    int z0 = (int)floorf(cz); int z1 = min(z0 + 1, DD - 1);
    int y0 = (int)floorf(cy); int y1 = min(y0 + 1, DD - 1);
    int x0 = (int)floorf(cx); int x1 = min(x0 + 1, DD - 1);
    float fz = cz - (float)z0;
    float fy = cy - (float)y0;
    float fx = cx - (float)x0;

    const float* ob = orig + (size_t)b * VOX;
    const float* mb = mask + (size_t)b * VOX;

    int i000 = (z0 * DD + y0) * DD + x0;
    int i001 = (z0 * DD + y0) * DD + x1;
    int i010 = (z0 * DD + y1) * DD + x0;
    int i011 = (z0 * DD + y1) * DD + x1;
    int i100 = (z1 * DD + y0) * DD + x0;
    int i101 = (z1 * DD + y0) * DD + x1;
    int i110 = (z1 * DD + y1) * DD + x0;
    int i111 = (z1 * DD + y1) * DD + x1;

    float gx0 = 1.f - fx, gy0 = 1.f - fy, gz0 = 1.f - fz;

    // orig
    float c00 = ob[i000] * gx0 + ob[i001] * fx;
    float c01 = ob[i010] * gx0 + ob[i011] * fx;
    float c10 = ob[i100] * gx0 + ob[i101] * fx;
    float c11 = ob[i110] * gx0 + ob[i111] * fx;
    float c0  = c00 * gy0 + c01 * fy;
    float c1  = c10 * gy0 + c11 * fy;
    out[idx] = c0 * gz0 + c1 * fz;

    // mask
    float m00 = mb[i000] * gx0 + mb[i001] * fx;
    float m01 = mb[i010] * gx0 + mb[i011] * fx;
    float m10 = mb[i100] * gx0 + mb[i101] * fx;
    float m11 = mb[i110] * gx0 + mb[i111] * fx;
    float m0  = m00 * gy0 + m01 * fy;
    float m1  = m10 * gy0 + m11 * fy;
    out[(size_t)NB * VOX + idx] = m0 * gz0 + m1 * fz;
}

extern "C" void kernel_launch(void* const* d_in, const int* in_sizes, int n_in,
                              void* d_out, int out_size, void* d_ws, size_t ws_size,
                              hipStream_t stream) {
    const float* enc   = (const float*)d_in[0];   // [8,128,5,5,5]
    const float* orig  = (const float*)d_in[1];   // [8,1,96,96,96]
    const float* mask  = (const float*)d_in[2];   // [8,1,96,96,96]
    const float* c1_w  = (const float*)d_in[3];   // [1,128,1,1,1]
    const float* c1_b  = (const float*)d_in[4];   // [1]
    const float* f1_w  = (const float*)d_in[5];   // [1,125]
    const float* f1_b  = (const float*)d_in[6];   // [1]
    const float* offs  = (const float*)d_in[7];   // [3,96,96,96]
    float* out = (float*)d_out;

    float* ws = (float*)d_ws;
    float* alpha = ws;                 // 8 floats
    float* bufA  = ws + 16;            // 3*VOX
    float* bufB  = bufA + 3 * VOX;     // 3*VOX

    alpha_kernel<<<NB, 256, 0, stream>>>(enc, c1_w, c1_b, f1_w, f1_b, alpha);

    int nF = 3 * VOX;
    int gF = (nF + 255) / 256;
    blur_axis<<<gF, 256, 0, stream>>>(offs, bufA, DD * DD);  // z pass
    blur_axis<<<gF, 256, 0, stream>>>(bufA, bufB, DD);       // y pass
    blur_x_final<<<gF, 256, 0, stream>>>(bufB, bufA);        // x pass + clip + scale

    int nS = NB * VOX;
    int gS = (nS + 255) / 256;
    sample_kernel<<<gS, 256, 0, stream>>>(orig, mask, bufA, alpha, out);
}

// Round 2
// 248.043 us; speedup vs baseline: 1.0790x; 1.0790x over previous
//
#include <hip/hip_runtime.h>
#include <math.h>

#define DD 96
#define VOX (96*96*96)
#define NB 8
#define NC 128
#define L3 125
#define V4 (VOX/4)        // float4s per channel
#define P4 (DD*DD/4)      // float4s per z-plane
#define R4 (DD/4)         // float4s per x-row
#define N4 (3*V4)

__device__ inline float4 f4add(float4 a, float4 b) {
    return make_float4(a.x + b.x, a.y + b.y, a.z + b.z, a.w + b.w);
}

// ---------------- alpha: per-batch sigmoid of double contraction -----------
__global__ void alpha_kernel(const float* __restrict__ enc,
                             const float* __restrict__ c1_w,
                             const float* __restrict__ c1_b,
                             const float* __restrict__ f1_w,
                             const float* __restrict__ f1_b,
                             float* __restrict__ alpha) {
    int b = blockIdx.x;
    int t = threadIdx.x;
    const float* e = enc + (size_t)b * NC * L3;
    float s = 0.f;
    for (int i = t; i < NC * L3; i += blockDim.x) {
        int c = i / L3;
        int v = i - c * L3;
        s += e[i] * c1_w[c] * f1_w[v];
    }
    for (int off = 32; off > 0; off >>= 1) s += __shfl_down(s, off, 64);
    __shared__ float red[4];
    int lane = t & 63, wid = t >> 6;
    if (lane == 0) red[wid] = s;
    __syncthreads();
    if (t == 0) {
        float tot = 0.f;
        for (int w = 0; w < (int)(blockDim.x >> 6); ++w) tot += red[w];
        float fwsum = 0.f;
        for (int v = 0; v < L3; ++v) fwsum += f1_w[v];
        float x = tot + c1_b[0] * fwsum + f1_b[0];
        alpha[b] = 1.f / (1.f + expf(-x));   // ALPHA_M = 1
    }
}

// ---------------- separable 7-tap box blur, float4-vectorized --------------
__global__ void blur_z(const float4* __restrict__ in, float4* __restrict__ out) {
    int idx = blockIdx.x * blockDim.x + threadIdx.x;
    if (idx >= N4) return;
    int v4 = idx % V4;
    int z = v4 / P4;
    float4 s = make_float4(0.f, 0.f, 0.f, 0.f);
    #pragma unroll
    for (int j = -3; j <= 3; ++j) {
        int q = z + j;
        if (q >= 0 && q < DD) s = f4add(s, in[idx + j * P4]);
    }
    out[idx] = s;
}

__global__ void blur_y(const float4* __restrict__ in, float4* __restrict__ out) {
    int idx = blockIdx.x * blockDim.x + threadIdx.x;
    if (idx >= N4) return;
    int v4 = idx % V4;
    int y = (v4 / R4) % DD;
    float4 s = make_float4(0.f, 0.f, 0.f, 0.f);
    #pragma unroll
    for (int j = -3; j <= 3; ++j) {
        int q = y + j;
        if (q >= 0 && q < DD) s = f4add(s, in[idx + j * R4]);
    }
    out[idx] = s;
}

// x pass + /343 + clip(+-0.01) + *96 (scale folded; zero-padded SAME)
__global__ void blur_x_final(const float4* __restrict__ in, float4* __restrict__ out) {
    int idx = blockIdx.x * blockDim.x + threadIdx.x;
    if (idx >= N4) return;
    int v4 = idx % V4;
    int gx = v4 % R4;     // float4 group within the 96-wide row
    float4 zero = make_float4(0.f, 0.f, 0.f, 0.f);
    float4 p = (gx > 0)      ? in[idx - 1] : zero;
    float4 c = in[idx];
    float4 n = (gx < R4 - 1) ? in[idx + 1] : zero;
    float w[12] = {p.x, p.y, p.z, p.w, c.x, c.y, c.z, c.w, n.x, n.y, n.z, n.w};
    float4 o;
    float* op = &o.x;
    #pragma unroll
    for (int j = 0; j < 4; ++j) {
        float s = 0.f;
        #pragma unroll
        for (int t = 1; t <= 7; ++t) s += w[j + t];
        s *= (1.0f / 343.0f);
        s = fminf(fmaxf(s, -0.01f), 0.01f);
        op[j] = s * 96.0f;
    }
    out[idx] = o;
}

// ---------------- trilinear sampling: thread per voxel, loop over batch ----
__global__ void sample_kernel(const float* __restrict__ orig,
                              const float* __restrict__ mask,
                              const float* __restrict__ field,
                              const float* __restrict__ alpha,
                              float* __restrict__ out) {
    int voxel = blockIdx.x * blockDim.x + threadIdx.x;
    if (voxel >= VOX) return;
    int z = voxel / (DD * DD);
    int y = (voxel / DD) % DD;
    int x = voxel % DD;

    float dz = field[voxel];
    float dy = field[VOX + voxel];
    float dx = field[2 * VOX + voxel];

    #pragma unroll 2
    for (int b = 0; b < NB; ++b) {
        float a = alpha[b];
        float cz = (float)z + a * dz;
        float cy = (float)y + a * dy;
        float cx = (float)x + a * dx;
        cz = fminf(fmaxf(cz, 0.f), (float)(DD - 1));
        cy = fminf(fmaxf(cy, 0.f), (float)(DD - 1));
        cx = fminf(fmaxf(cx, 0.f), (float)(DD - 1));

        int z0 = (int)floorf(cz); int z1 = min(z0 + 1, DD - 1);
        int y0 = (int)floorf(cy); int y1 = min(y0 + 1, DD - 1);
        int x0 = (int)floorf(cx); int x1 = min(x0 + 1, DD - 1);
        float fz = cz - (float)z0;
        float fy = cy - (float)y0;
        float fx = cx - (float)x0;
        float gz = 1.f - fz, gy = 1.f - fy, gx = 1.f - fx;

        const float* ob = orig + (size_t)b * VOX;
        const float* mb = mask + (size_t)b * VOX;

        int i000 = (z0 * DD + y0) * DD + x0;
        int i001 = (z0 * DD + y0) * DD + x1;
        int i010 = (z0 * DD + y1) * DD + x0;
        int i011 = (z0 * DD + y1) * DD + x1;
        int i100 = (z1 * DD + y0) * DD + x0;
        int i101 = (z1 * DD + y0) * DD + x1;
        int i110 = (z1 * DD + y1) * DD + x0;
        int i111 = (z1 * DD + y1) * DD + x1;

        float c00 = ob[i000] * gx + ob[i001] * fx;
        float c01 = ob[i010] * gx + ob[i011] * fx;
        float c10 = ob[i100] * gx + ob[i101] * fx;
        float c11 = ob[i110] * gx + ob[i111] * fx;
        float m00 = mb[i000] * gx + mb[i001] * fx;
        float m01 = mb[i010] * gx + mb[i011] * fx;
        float m10 = mb[i100] * gx + mb[i101] * fx;
        float m11 = mb[i110] * gx + mb[i111] * fx;

        float c0 = c00 * gy + c01 * fy;
        float c1 = c10 * gy + c11 * fy;
        float m0 = m00 * gy + m01 * fy;
        float m1 = m10 * gy + m11 * fy;

        out[(size_t)b * VOX + voxel] = c0 * gz + c1 * fz;
        out[(size_t)NB * VOX + (size_t)b * VOX + voxel] = m0 * gz + m1 * fz;
    }
}

extern "C" void kernel_launch(void* const* d_in, const int* in_sizes, int n_in,
                              void* d_out, int out_size, void* d_ws, size_t ws_size,
                              hipStream_t stream) {
    const float* enc   = (const float*)d_in[0];
    const float* orig  = (const float*)d_in[1];
    const float* mask  = (const float*)d_in[2];
    const float* c1_w  = (const float*)d_in[3];
    const float* c1_b  = (const float*)d_in[4];
    const float* f1_w  = (const float*)d_in[5];
    const float* f1_b  = (const float*)d_in[6];
    const float* offs  = (const float*)d_in[7];
    float* out = (float*)d_out;

    float* ws = (float*)d_ws;
    float* alpha = ws;                 // 8 floats (offset 0, 16B aligned)
    float* bufA  = ws + 16;            // 3*VOX floats, 64B-aligned
    float* bufB  = bufA + 3 * VOX;

    alpha_kernel<<<NB, 256, 0, stream>>>(enc, c1_w, c1_b, f1_w, f1_b, alpha);

    int g4 = (N4 + 255) / 256;
    blur_z<<<g4, 256, 0, stream>>>((const float4*)offs, (float4*)bufA);
    blur_y<<<g4, 256, 0, stream>>>((const float4*)bufA, (float4*)bufB);
    blur_x_final<<<g4, 256, 0, stream>>>((const float4*)bufB, (float4*)bufA);

    int gS = (VOX + 255) / 256;
    sample_kernel<<<gS, 256, 0, stream>>>(orig, mask, bufA, alpha, out);
}

// Round 3
// 233.426 us; speedup vs baseline: 1.1465x; 1.0626x over previous
//
#include <hip/hip_runtime.h>
#include <math.h>

#define DD 96
#define VOX (96*96*96)
#define NB 8
#define NC 128
#define L3 125
#define V4 (VOX/4)
#define P4 (DD*DD/4)
#define R4 (DD/4)
#define N4 (3*V4)

#define TS 16            // tile size per dim
#define NT 6             // tiles per dim (96/16)
#define NTILE (NT*NT*NT) // 216
#define HS 18            // halo side (TS+2)
#define HVOL (HS*HS*HS)  // 5832

__device__ inline float4 f4add(float4 a, float4 b) {
    return make_float4(a.x + b.x, a.y + b.y, a.z + b.z, a.w + b.w);
}

// ---------------- alpha: per-batch sigmoid of double contraction -----------
__global__ void alpha_kernel(const float* __restrict__ enc,
                             const float* __restrict__ c1_w,
                             const float* __restrict__ c1_b,
                             const float* __restrict__ f1_w,
                             const float* __restrict__ f1_b,
                             float* __restrict__ alpha) {
    int b = blockIdx.x;
    int t = threadIdx.x;
    const float* e = enc + (size_t)b * NC * L3;
    float s = 0.f;
    for (int i = t; i < NC * L3; i += blockDim.x) {
        int c = i / L3;
        int v = i - c * L3;
        s += e[i] * c1_w[c] * f1_w[v];
    }
    for (int off = 32; off > 0; off >>= 1) s += __shfl_down(s, off, 64);
    __shared__ float red[4];
    int lane = t & 63, wid = t >> 6;
    if (lane == 0) red[wid] = s;
    __syncthreads();
    if (t == 0) {
        float tot = 0.f;
        for (int w = 0; w < (int)(blockDim.x >> 6); ++w) tot += red[w];
        float fwsum = 0.f;
        for (int v = 0; v < L3; ++v) fwsum += f1_w[v];
        float x = tot + c1_b[0] * fwsum + f1_b[0];
        alpha[b] = 1.f / (1.f + expf(-x));   // ALPHA_M = 1
    }
}

// ---------------- separable 7-tap box blur, float4-vectorized --------------
__global__ void blur_z(const float4* __restrict__ in, float4* __restrict__ out) {
    int idx = blockIdx.x * blockDim.x + threadIdx.x;
    if (idx >= N4) return;
    int v4 = idx % V4;
    int z = v4 / P4;
    float4 s = make_float4(0.f, 0.f, 0.f, 0.f);
    #pragma unroll
    for (int j = -3; j <= 3; ++j) {
        int q = z + j;
        if (q >= 0 && q < DD) s = f4add(s, in[idx + j * P4]);
    }
    out[idx] = s;
}

__global__ void blur_y(const float4* __restrict__ in, float4* __restrict__ out) {
    int idx = blockIdx.x * blockDim.x + threadIdx.x;
    if (idx >= N4) return;
    int v4 = idx % V4;
    int y = (v4 / R4) % DD;
    float4 s = make_float4(0.f, 0.f, 0.f, 0.f);
    #pragma unroll
    for (int j = -3; j <= 3; ++j) {
        int q = y + j;
        if (q >= 0 && q < DD) s = f4add(s, in[idx + j * R4]);
    }
    out[idx] = s;
}

__global__ void blur_x_final(const float4* __restrict__ in, float4* __restrict__ out) {
    int idx = blockIdx.x * blockDim.x + threadIdx.x;
    if (idx >= N4) return;
    int v4 = idx % V4;
    int gx = v4 % R4;
    float4 zero = make_float4(0.f, 0.f, 0.f, 0.f);
    float4 p = (gx > 0)      ? in[idx - 1] : zero;
    float4 c = in[idx];
    float4 n = (gx < R4 - 1) ? in[idx + 1] : zero;
    float w[12] = {p.x, p.y, p.z, p.w, c.x, c.y, c.z, c.w, n.x, n.y, n.z, n.w};
    float4 o;
    float* op = &o.x;
    #pragma unroll
    for (int j = 0; j < 4; ++j) {
        float s = 0.f;
        #pragma unroll
        for (int t = 1; t <= 7; ++t) s += w[j + t];
        s *= (1.0f / 343.0f);
        s = fminf(fmaxf(s, -0.01f), 0.01f);
        op[j] = s * 96.0f;
    }
    out[idx] = o;
}

// ---------------- tiled trilinear sampling -----------------------------------
// |disp| <= 0.96 voxel => all 8 corners lie in [g-1, g+1]^3: a 3x3x3 stencil.
// Stage an 18^3 halo of (orig,mask) interleaved in LDS; gather from LDS.
// blockIdx.x = b*NTILE + tile  (b slow: 216%8==0 keeps a tile's 8 batch-blocks
// on one XCD so the field tile stays L2-resident across batches).
__global__ __launch_bounds__(256) void sample_tile(
        const float* __restrict__ orig,
        const float* __restrict__ mask,
        const float* __restrict__ field,
        const float* __restrict__ alpha,
        float* __restrict__ out) {
    __shared__ float2 tile[HVOL];

    int blk = blockIdx.x;
    int b = blk / NTILE;
    int t = blk - b * NTILE;
    int tz = t / (NT * NT);
    int ty = (t / NT) % NT;
    int tx = t % NT;
    int bz = tz * TS, by = ty * TS, bx = tx * TS;

    const float* ob = orig + (size_t)b * VOX;
    const float* mb = mask + (size_t)b * VOX;
    int tid = threadIdx.x;

    // halo load (clamped at volume edges — clamped cells are never read by
    // the interp since reference indices stay in [0,95])
    for (int i = tid; i < HVOL; i += 256) {
        int hz = i / (HS * HS);
        int hy = (i / HS) % HS;
        int hx = i % HS;
        int gz = min(max(bz + hz - 1, 0), DD - 1);
        int gy = min(max(by + hy - 1, 0), DD - 1);
        int gx = min(max(bx + hx - 1, 0), DD - 1);
        int g = (gz * DD + gy) * DD + gx;
        tile[i] = make_float2(ob[g], mb[g]);
    }
    float a = alpha[b];
    __syncthreads();

    #pragma unroll 4
    for (int it = 0; it < (TS * TS * TS) / 256; ++it) {
        int v = it * 256 + tid;
        int lz = v >> 8;          // v / 256
        int ly = (v >> 4) & 15;
        int lx = v & 15;
        int gz = bz + lz, gy = by + ly, gx = bx + lx;
        int voxel = (gz * DD + gy) * DD + gx;

        float cz = (float)gz + a * field[voxel];
        float cy = (float)gy + a * field[VOX + voxel];
        float cx = (float)gx + a * field[2 * VOX + voxel];
        cz = fminf(fmaxf(cz, 0.f), (float)(DD - 1));
        cy = fminf(fmaxf(cy, 0.f), (float)(DD - 1));
        cx = fminf(fmaxf(cx, 0.f), (float)(DD - 1));

        int z0 = (int)floorf(cz); int z1 = min(z0 + 1, DD - 1);
        int y0 = (int)floorf(cy); int y1 = min(y0 + 1, DD - 1);
        int x0 = (int)floorf(cx); int x1 = min(x0 + 1, DD - 1);
        float fz = cz - (float)z0;
        float fy = cy - (float)y0;
        float fx = cx - (float)x0;
        float qz = 1.f - fz, qy = 1.f - fy, qx = 1.f - fx;

        // local halo coords (guaranteed in [0,17])
        int hz0 = z0 - bz + 1, hz1 = z1 - bz + 1;
        int hy0 = y0 - by + 1, hy1 = y1 - by + 1;
        int hx0 = x0 - bx + 1, hx1 = x1 - bx + 1;

        int r00 = (hz0 * HS + hy0) * HS;
        int r01 = (hz0 * HS + hy1) * HS;
        int r10 = (hz1 * HS + hy0) * HS;
        int r11 = (hz1 * HS + hy1) * HS;

        float2 v000 = tile[r00 + hx0], v001 = tile[r00 + hx1];
        float2 v010 = tile[r01 + hx0], v011 = tile[r01 + hx1];
        float2 v100 = tile[r10 + hx0], v101 = tile[r10 + hx1];
        float2 v110 = tile[r11 + hx0], v111 = tile[r11 + hx1];

        float c00 = v000.x * qx + v001.x * fx;
        float c01 = v010.x * qx + v011.x * fx;
        float c10 = v100.x * qx + v101.x * fx;
        float c11 = v110.x * qx + v111.x * fx;
        float m00 = v000.y * qx + v001.y * fx;
        float m01 = v010.y * qx + v011.y * fx;
        float m10 = v100.y * qx + v101.y * fx;
        float m11 = v110.y * qx + v111.y * fx;

        float c0 = c00 * qy + c01 * fy;
        float c1 = c10 * qy + c11 * fy;
        float m0 = m00 * qy + m01 * fy;
        float m1 = m10 * qy + m11 * fy;

        out[(size_t)b * VOX + voxel] = c0 * qz + c1 * fz;
        out[(size_t)NB * VOX + (size_t)b * VOX + voxel] = m0 * qz + m1 * fz;
    }
}

extern "C" void kernel_launch(void* const* d_in, const int* in_sizes, int n_in,
                              void* d_out, int out_size, void* d_ws, size_t ws_size,
                              hipStream_t stream) {
    const float* enc   = (const float*)d_in[0];
    const float* orig  = (const float*)d_in[1];
    const float* mask  = (const float*)d_in[2];
    const float* c1_w  = (const float*)d_in[3];
    const float* c1_b  = (const float*)d_in[4];
    const float* f1_w  = (const float*)d_in[5];
    const float* f1_b  = (const float*)d_in[6];
    const float* offs  = (const float*)d_in[7];
    float* out = (float*)d_out;

    float* ws = (float*)d_ws;
    float* alpha = ws;                 // 8 floats
    float* bufA  = ws + 16;            // 3*VOX floats, 64B aligned
    float* bufB  = bufA + 3 * VOX;

    alpha_kernel<<<NB, 256, 0, stream>>>(enc, c1_w, c1_b, f1_w, f1_b, alpha);

    int g4 = (N4 + 255) / 256;
    blur_z<<<g4, 256, 0, stream>>>((const float4*)offs, (float4*)bufA);
    blur_y<<<g4, 256, 0, stream>>>((const float4*)bufA, (float4*)bufB);
    blur_x_final<<<g4, 256, 0, stream>>>((const float4*)bufB, (float4*)bufA);

    sample_tile<<<NB * NTILE, 256, 0, stream>>>(orig, mask, bufA, alpha, out);
}

// Round 4
// 212.270 us; speedup vs baseline: 1.2608x; 1.0997x over previous
//
#include <hip/hip_runtime.h>
#include <math.h>

#define DD 96
#define VOX (96*96*96)
#define NB 8
#define NC 128
#define L3 125

#define TS 16            // sample tile size per dim
#define NT 6             // tiles per dim (96/16)
#define NTILE (NT*NT*NT) // 216
#define HS 18            // halo side (TS+2)
#define HVOL (HS*HS*HS)  // 5832

// ---------------- alpha: per-batch sigmoid of double contraction -----------
__global__ void alpha_kernel(const float* __restrict__ enc,
                             const float* __restrict__ c1_w,
                             const float* __restrict__ c1_b,
                             const float* __restrict__ f1_w,
                             const float* __restrict__ f1_b,
                             float* __restrict__ alpha) {
    int b = blockIdx.x;
    int t = threadIdx.x;
    const float4* e4 = (const float4*)(enc + (size_t)b * NC * L3);
    float s = 0.f;
    for (int j = t; j < (NC * L3) / 4; j += 256) {   // 16000/4 = 4000
        float4 v = e4[j];
        int f = j * 4;
        s += v.x * c1_w[(f + 0) / L3] * f1_w[(f + 0) % L3];
        s += v.y * c1_w[(f + 1) / L3] * f1_w[(f + 1) % L3];
        s += v.z * c1_w[(f + 2) / L3] * f1_w[(f + 2) % L3];
        s += v.w * c1_w[(f + 3) / L3] * f1_w[(f + 3) % L3];
    }
    for (int off = 32; off > 0; off >>= 1) s += __shfl_down(s, off, 64);
    __shared__ float red[4];
    int lane = t & 63, wid = t >> 6;
    if (lane == 0) red[wid] = s;
    __syncthreads();
    if (t == 0) {
        float tot = red[0] + red[1] + red[2] + red[3];
        float fwsum = 0.f;
        for (int v = 0; v < L3; ++v) fwsum += f1_w[v];
        float x = tot + c1_b[0] * fwsum + f1_b[0];
        alpha[b] = 1.f / (1.f + expf(-x));   // ALPHA_M = 1
    }
}

// ---------------- blur pass A: 7-tap along z (zero pad), LDS row tiles -----
// grid: 3ch * 96y * 6 z-strips; block 256
__global__ __launch_bounds__(256) void blur_z_tile(const float* __restrict__ in,
                                                   float* __restrict__ out) {
    __shared__ float rows[22][DD];
    int blk = blockIdx.x;
    int zs = blk % NT;
    int y  = (blk / NT) % DD;
    int c  = blk / (NT * DD);
    int z0 = zs * TS;
    int tid = threadIdx.x;

    const float* base = in + (size_t)c * VOX + y * DD;
    for (int i = tid; i < 22 * DD; i += 256) {
        int r = i / DD, x = i - (i / DD) * DD;
        int z = z0 - 3 + r;
        rows[r][x] = (z >= 0 && z < DD) ? base[z * DD * DD + x] : 0.f;
    }
    __syncthreads();
    float* ob = out + (size_t)c * VOX + y * DD;
    for (int i = tid; i < TS * DD; i += 256) {
        int r = i / DD, x = i - (i / DD) * DD;
        float s = rows[r][x] + rows[r+1][x] + rows[r+2][x] + rows[r+3][x]
                + rows[r+4][x] + rows[r+5][x] + rows[r+6][x];
        ob[(z0 + r) * DD * DD + x] = s;
    }
}

// ---------------- blur pass B: 7-tap along y, then x + /343 + clip + *96 ---
// grid: 3ch * 96z * 6 y-strips; block 256
__global__ __launch_bounds__(256) void blur_yx_tile(const float* __restrict__ in,
                                                    float* __restrict__ out) {
    __shared__ float rows[22][DD];
    __shared__ float yb[TS][DD];
    int blk = blockIdx.x;
    int ys = blk % NT;
    int z  = (blk / NT) % DD;
    int c  = blk / (NT * DD);
    int y0 = ys * TS;
    int tid = threadIdx.x;

    const float* base = in + (size_t)c * VOX + z * DD * DD;
    for (int i = tid; i < 22 * DD; i += 256) {
        int r = i / DD, x = i - (i / DD) * DD;
        int y = y0 - 3 + r;
        rows[r][x] = (y >= 0 && y < DD) ? base[y * DD + x] : 0.f;
    }
    __syncthreads();
    for (int i = tid; i < TS * DD; i += 256) {
        int r = i / DD, x = i - (i / DD) * DD;
        yb[r][x] = rows[r][x] + rows[r+1][x] + rows[r+2][x] + rows[r+3][x]
                 + rows[r+4][x] + rows[r+5][x] + rows[r+6][x];
    }
    __syncthreads();
    float* ob = out + (size_t)c * VOX + z * DD * DD;
    for (int i = tid; i < TS * DD; i += 256) {
        int r = i / DD, x = i - (i / DD) * DD;
        float s = 0.f;
        #pragma unroll
        for (int j = -3; j <= 3; ++j) {
            int q = x + j;
            if (q >= 0 && q < DD) s += yb[r][q];
        }
        s *= (1.0f / 343.0f);
        s = fminf(fmaxf(s, -0.01f), 0.01f);
        ob[(y0 + r) * DD + x] = s * 96.0f;
    }
}

// ---------------- tiled trilinear sampling (unchanged from R3) -------------
__global__ __launch_bounds__(256) void sample_tile(
        const float* __restrict__ orig,
        const float* __restrict__ mask,
        const float* __restrict__ field,
        const float* __restrict__ alpha,
        float* __restrict__ out) {
    __shared__ float2 tile[HVOL];

    int blk = blockIdx.x;
    int b = blk / NTILE;
    int t = blk - b * NTILE;
    int tz = t / (NT * NT);
    int ty = (t / NT) % NT;
    int tx = t % NT;
    int bz = tz * TS, by = ty * TS, bx = tx * TS;

    const float* ob = orig + (size_t)b * VOX;
    const float* mb = mask + (size_t)b * VOX;
    int tid = threadIdx.x;

    for (int i = tid; i < HVOL; i += 256) {
        int hz = i / (HS * HS);
        int hy = (i / HS) % HS;
        int hx = i % HS;
        int gz = min(max(bz + hz - 1, 0), DD - 1);
        int gy = min(max(by + hy - 1, 0), DD - 1);
        int gx = min(max(bx + hx - 1, 0), DD - 1);
        int g = (gz * DD + gy) * DD + gx;
        tile[i] = make_float2(ob[g], mb[g]);
    }
    float a = alpha[b];
    __syncthreads();

    #pragma unroll 4
    for (int it = 0; it < (TS * TS * TS) / 256; ++it) {
        int v = it * 256 + tid;
        int lz = v >> 8;
        int ly = (v >> 4) & 15;
        int lx = v & 15;
        int gz = bz + lz, gy = by + ly, gx = bx + lx;
        int voxel = (gz * DD + gy) * DD + gx;

        float cz = (float)gz + a * field[voxel];
        float cy = (float)gy + a * field[VOX + voxel];
        float cx = (float)gx + a * field[2 * VOX + voxel];
        cz = fminf(fmaxf(cz, 0.f), (float)(DD - 1));
        cy = fminf(fmaxf(cy, 0.f), (float)(DD - 1));
        cx = fminf(fmaxf(cx, 0.f), (float)(DD - 1));

        int z0 = (int)floorf(cz); int z1 = min(z0 + 1, DD - 1);
        int y0 = (int)floorf(cy); int y1 = min(y0 + 1, DD - 1);
        int x0 = (int)floorf(cx); int x1 = min(x0 + 1, DD - 1);
        float fz = cz - (float)z0;
        float fy = cy - (float)y0;
        float fx = cx - (float)x0;
        float qz = 1.f - fz, qy = 1.f - fy, qx = 1.f - fx;

        int hz0 = z0 - bz + 1, hz1 = z1 - bz + 1;
        int hy0 = y0 - by + 1, hy1 = y1 - by + 1;
        int hx0 = x0 - bx + 1, hx1 = x1 - bx + 1;

        int r00 = (hz0 * HS + hy0) * HS;
        int r01 = (hz0 * HS + hy1) * HS;
        int r10 = (hz1 * HS + hy0) * HS;
        int r11 = (hz1 * HS + hy1) * HS;

        float2 v000 = tile[r00 + hx0], v001 = tile[r00 + hx1];
        float2 v010 = tile[r01 + hx0], v011 = tile[r01 + hx1];
        float2 v100 = tile[r10 + hx0], v101 = tile[r10 + hx1];
        float2 v110 = tile[r11 + hx0], v111 = tile[r11 + hx1];

        float c00 = v000.x * qx + v001.x * fx;
        float c01 = v010.x * qx + v011.x * fx;
        float c10 = v100.x * qx + v101.x * fx;
        float c11 = v110.x * qx + v111.x * fx;
        float m00 = v000.y * qx + v001.y * fx;
        float m01 = v010.y * qx + v011.y * fx;
        float m10 = v100.y * qx + v101.y * fx;
        float m11 = v110.y * qx + v111.y * fx;

        float c0 = c00 * qy + c01 * fy;
        float c1 = c10 * qy + c11 * fy;
        float m0 = m00 * qy + m01 * fy;
        float m1 = m10 * qy + m11 * fy;

        out[(size_t)b * VOX + voxel] = c0 * qz + c1 * fz;
        out[(size_t)NB * VOX + (size_t)b * VOX + voxel] = m0 * qz + m1 * fz;
    }
}

extern "C" void kernel_launch(void* const* d_in, const int* in_sizes, int n_in,
                              void* d_out, int out_size, void* d_ws, size_t ws_size,
                              hipStream_t stream) {
    const float* enc   = (const float*)d_in[0];
    const float* orig  = (const float*)d_in[1];
    const float* mask  = (const float*)d_in[2];
    const float* c1_w  = (const float*)d_in[3];
    const float* c1_b  = (const float*)d_in[4];
    const float* f1_w  = (const float*)d_in[5];
    const float* f1_b  = (const float*)d_in[6];
    const float* offs  = (const float*)d_in[7];
    float* out = (float*)d_out;

    float* ws = (float*)d_ws;
    float* alpha = ws;                 // 8 floats
    float* bufA  = ws + 16;            // 3*VOX floats (z-blurred)
    float* bufB  = bufA + 3 * VOX;     // 3*VOX floats (final field)

    alpha_kernel<<<NB, 256, 0, stream>>>(enc, c1_w, c1_b, f1_w, f1_b, alpha);

    int gB = 3 * DD * NT;   // 1728 blocks per pass
    blur_z_tile<<<gB, 256, 0, stream>>>(offs, bufA);
    blur_yx_tile<<<gB, 256, 0, stream>>>(bufA, bufB);

    sample_tile<<<NB * NTILE, 256, 0, stream>>>(orig, mask, bufB, alpha, out);
}

// Round 5
// 203.750 us; speedup vs baseline: 1.3135x; 1.0418x over previous
//
#include <hip/hip_runtime.h>
#include <hip/hip_fp16.h>
#include <math.h>

#define DD 96
#define VOX (96*96*96)
#define NB 8
#define NC 128
#define L3 125

#define TS 16            // sample tile size per dim
#define NT 6             // tiles per dim (96/16)
#define NTILE (NT*NT*NT) // 216
#define HS 18            // sample halo side (TS+2)
#define HVOL (HS*HS*HS)  // 5832

#define BHS 22           // blur halo side (16+6)

// ---------------- alpha: per-batch sigmoid of double contraction -----------
__global__ void alpha_kernel(const float* __restrict__ enc,
                             const float* __restrict__ c1_w,
                             const float* __restrict__ c1_b,
                             const float* __restrict__ f1_w,
                             const float* __restrict__ f1_b,
                             float* __restrict__ alpha) {
    int b = blockIdx.x;
    int t = threadIdx.x;
    const float4* e4 = (const float4*)(enc + (size_t)b * NC * L3);
    float s = 0.f;
    for (int j = t; j < (NC * L3) / 4; j += 256) {
        float4 v = e4[j];
        int f = j * 4;
        s += v.x * c1_w[(f + 0) / L3] * f1_w[(f + 0) % L3];
        s += v.y * c1_w[(f + 1) / L3] * f1_w[(f + 1) % L3];
        s += v.z * c1_w[(f + 2) / L3] * f1_w[(f + 2) % L3];
        s += v.w * c1_w[(f + 3) / L3] * f1_w[(f + 3) % L3];
    }
    for (int off = 32; off > 0; off >>= 1) s += __shfl_down(s, off, 64);
    __shared__ float red[4];
    int lane = t & 63, wid = t >> 6;
    if (lane == 0) red[wid] = s;
    __syncthreads();
    if (t == 0) {
        float tot = red[0] + red[1] + red[2] + red[3];
        float fwsum = 0.f;
        for (int v = 0; v < L3; ++v) fwsum += f1_w[v];
        float x = tot + c1_b[0] * fwsum + f1_b[0];
        alpha[b] = 1.f / (1.f + expf(-x));   // ALPHA_M = 1
    }
}

// ---------------- fused 3D 7^3 box blur + clip + scale ---------------------
// one block per (channel, 16^3 tile): 22^3 halo in LDS, separable z->y->x
// with sliding-window sums; final /343, clip(+-0.01), *96, coalesced store.
__global__ __launch_bounds__(256) void blur3d(const float* __restrict__ in,
                                              float* __restrict__ out) {
    __shared__ float h[BHS * BHS * BHS];   // 10648 floats = 42.6 KB
    __shared__ float zb[TS * BHS * BHS];   // 7744 floats  = 31.0 KB
    float* yb = h;                          // reuse h after z-blur (16*16*22)

    int blk = blockIdx.x;
    int c = blk / NTILE;
    int t = blk % NTILE;
    int tz = t / (NT * NT), ty = (t / NT) % NT, tx = t % NT;
    int bz = tz * TS, by = ty * TS, bx = tx * TS;
    const float* ib = in + (size_t)c * VOX;
    int tid = threadIdx.x;

    for (int i = tid; i < BHS * BHS * BHS; i += 256) {
        int hz = i / (BHS * BHS);
        int hy = (i / BHS) % BHS;
        int hx = i % BHS;
        int gz = bz + hz - 3, gy = by + hy - 3, gx = bx + hx - 3;
        float v = 0.f;
        if (gz >= 0 && gz < DD && gy >= 0 && gy < DD && gx >= 0 && gx < DD)
            v = ib[(gz * DD + gy) * DD + gx];
        h[i] = v;
    }
    __syncthreads();

    // z-blur: columns over (hy,hx), sliding window
    for (int cc = tid; cc < BHS * BHS; cc += 256) {
        float s = 0.f;
        #pragma unroll
        for (int z = 0; z < 7; ++z) s += h[z * (BHS * BHS) + cc];
        zb[cc] = s;
        for (int z = 1; z < TS; ++z) {
            s += h[(z + 6) * (BHS * BHS) + cc] - h[(z - 1) * (BHS * BHS) + cc];
            zb[z * (BHS * BHS) + cc] = s;
        }
    }
    __syncthreads();   // all reads of h done; safe to overwrite as yb

    // y-blur: columns over (z,hx), sliding window; yb[z][y][hx] 16x16x22
    for (int cc = tid; cc < TS * BHS; cc += 256) {
        int z = cc / BHS, hx = cc % BHS;
        const float* zp = zb + z * (BHS * BHS) + hx;
        float s = 0.f;
        #pragma unroll
        for (int y = 0; y < 7; ++y) s += zp[y * BHS];
        yb[(z * TS) * BHS + hx] = s;
        for (int y = 1; y < TS; ++y) {
            s += zp[(y + 6) * BHS] - zp[(y - 1) * BHS];
            yb[(z * TS + y) * BHS + hx] = s;
        }
    }
    __syncthreads();

    // x-blur direct 7-tap + normalize/clip/scale, coalesced store
    float* ob = out + (size_t)c * VOX;
    for (int i = tid; i < TS * TS * TS; i += 256) {
        int z = i >> 8, y = (i >> 4) & 15, x = i & 15;
        const float* yp = yb + (z * TS + y) * BHS;
        float s = yp[x] + yp[x + 1] + yp[x + 2] + yp[x + 3]
                + yp[x + 4] + yp[x + 5] + yp[x + 6];
        s *= (1.0f / 343.0f);
        s = fminf(fmaxf(s, -0.01f), 0.01f);
        ob[((bz + z) * DD + (by + y)) * DD + (bx + x)] = s * 96.0f;
    }
}

// ---------------- tiled trilinear sampling ---------------------------------
// half2 (orig,mask) halo in LDS (23.3 KB -> 6 blocks/CU); octant XCD swizzle
// pins each 3x3x3 tile-octant to one XCD across all batches.
__global__ __launch_bounds__(256) void sample_tile(
        const float* __restrict__ orig,
        const float* __restrict__ mask,
        const float* __restrict__ field,
        const float* __restrict__ alpha,
        float* __restrict__ out) {
    __shared__ __half2 tile[HVOL];

    int blk = blockIdx.x;
    int b = blk / NTILE;
    int r = blk % NTILE;
    int l = r >> 3;        // 0..26 within octant
    int o = r & 7;         // octant -> XCD (216 % 8 == 0, consecutive IDs RR)
    int lz = l / 9, ly = (l / 3) % 3, lx3 = l % 3;
    int tz = ((o >> 2) & 1) * 3 + lz;
    int ty = ((o >> 1) & 1) * 3 + ly;
    int tx = (o & 1) * 3 + lx3;
    int bz = tz * TS, by = ty * TS, bx = tx * TS;

    const float* ob = orig + (size_t)b * VOX;
    const float* mb = mask + (size_t)b * VOX;
    int tid = threadIdx.x;

    for (int i = tid; i < HVOL; i += 256) {
        int hz = i / (HS * HS);
        int hy = (i / HS) % HS;
        int hx = i % HS;
        int gz = min(max(bz + hz - 1, 0), DD - 1);
        int gy = min(max(by + hy - 1, 0), DD - 1);
        int gx = min(max(bx + hx - 1, 0), DD - 1);
        int g = (gz * DD + gy) * DD + gx;
        tile[i] = __floats2half2_rn(ob[g], mb[g]);
    }
    float a = alpha[b];
    __syncthreads();

    #pragma unroll 4
    for (int it = 0; it < (TS * TS * TS) / 256; ++it) {
        int v = it * 256 + tid;
        int lz2 = v >> 8;
        int ly2 = (v >> 4) & 15;
        int lx2 = v & 15;
        int gz = bz + lz2, gy = by + ly2, gx = bx + lx2;
        int voxel = (gz * DD + gy) * DD + gx;

        float cz = (float)gz + a * field[voxel];
        float cy = (float)gy + a * field[VOX + voxel];
        float cx = (float)gx + a * field[2 * VOX + voxel];
        cz = fminf(fmaxf(cz, 0.f), (float)(DD - 1));
        cy = fminf(fmaxf(cy, 0.f), (float)(DD - 1));
        cx = fminf(fmaxf(cx, 0.f), (float)(DD - 1));

        int z0 = (int)floorf(cz); int z1 = min(z0 + 1, DD - 1);
        int y0 = (int)floorf(cy); int y1 = min(y0 + 1, DD - 1);
        int x0 = (int)floorf(cx); int x1 = min(x0 + 1, DD - 1);
        float fz = cz - (float)z0;
        float fy = cy - (float)y0;
        float fx = cx - (float)x0;
        float qz = 1.f - fz, qy = 1.f - fy, qx = 1.f - fx;

        int hz0 = z0 - bz + 1, hz1 = z1 - bz + 1;
        int hy0 = y0 - by + 1, hy1 = y1 - by + 1;
        int hx0 = x0 - bx + 1, hx1 = x1 - bx + 1;

        int r00 = (hz0 * HS + hy0) * HS;
        int r01 = (hz0 * HS + hy1) * HS;
        int r10 = (hz1 * HS + hy0) * HS;
        int r11 = (hz1 * HS + hy1) * HS;

        float2 v000 = __half22float2(tile[r00 + hx0]);
        float2 v001 = __half22float2(tile[r00 + hx1]);
        float2 v010 = __half22float2(tile[r01 + hx0]);
        float2 v011 = __half22float2(tile[r01 + hx1]);
        float2 v100 = __half22float2(tile[r10 + hx0]);
        float2 v101 = __half22float2(tile[r10 + hx1]);
        float2 v110 = __half22float2(tile[r11 + hx0]);
        float2 v111 = __half22float2(tile[r11 + hx1]);

        float c00 = v000.x * qx + v001.x * fx;
        float c01 = v010.x * qx + v011.x * fx;
        float c10 = v100.x * qx + v101.x * fx;
        float c11 = v110.x * qx + v111.x * fx;
        float m00 = v000.y * qx + v001.y * fx;
        float m01 = v010.y * qx + v011.y * fx;
        float m10 = v100.y * qx + v101.y * fx;
        float m11 = v110.y * qx + v111.y * fx;

        float c0 = c00 * qy + c01 * fy;
        float c1 = c10 * qy + c11 * fy;
        float m0 = m00 * qy + m01 * fy;
        float m1 = m10 * qy + m11 * fy;

        __builtin_nontemporal_store(c0 * qz + c1 * fz,
                                    &out[(size_t)b * VOX + voxel]);
        __builtin_nontemporal_store(m0 * qz + m1 * fz,
                                    &out[(size_t)NB * VOX + (size_t)b * VOX + voxel]);
    }
}

extern "C" void kernel_launch(void* const* d_in, const int* in_sizes, int n_in,
                              void* d_out, int out_size, void* d_ws, size_t ws_size,
                              hipStream_t stream) {
    const float* enc   = (const float*)d_in[0];
    const float* orig  = (const float*)d_in[1];
    const float* mask  = (const float*)d_in[2];
    const float* c1_w  = (const float*)d_in[3];
    const float* c1_b  = (const float*)d_in[4];
    const float* f1_w  = (const float*)d_in[5];
    const float* f1_b  = (const float*)d_in[6];
    const float* offs  = (const float*)d_in[7];
    float* out = (float*)d_out;

    float* ws = (float*)d_ws;
    float* alpha = ws;                 // 8 floats
    float* fieldB = ws + 16;           // 3*VOX floats (final blurred field)

    alpha_kernel<<<NB, 256, 0, stream>>>(enc, c1_w, c1_b, f1_w, f1_b, alpha);
    blur3d<<<3 * NTILE, 256, 0, stream>>>(offs, fieldB);
    sample_tile<<<NB * NTILE, 256, 0, stream>>>(orig, mask, fieldB, alpha, out);
}

// Round 7
// 201.758 us; speedup vs baseline: 1.3265x; 1.0099x over previous
//
#include <hip/hip_runtime.h>
#include <hip/hip_fp16.h>
#include <math.h>

#define DD 96
#define VOX (96*96*96)
#define NB 8
#define NC 128
#define L3 125

// ---- blur tiling (unchanged) ----
#define BTS 16
#define BNT 6
#define BNTILE (BNT*BNT*BNT)   // 216
#define BHS 22

// ---- sample tiling: (z,y,x) = (8,16,32) ----
#define TZ 8
#define TY 16
#define TX 32
#define NTZ 12
#define NTY 6
#define NTX 3
#define STILE (NTZ*NTY*NTX)    // 216
#define HZS 10
#define HYS 18
#define HXS 34
#define HXP 35                 // padded row stride (odd -> bank-friendly)
#define HN (HZS*HYS*HXS)       // 6120 elements to stage
#define HLDS (HZS*HYS*HXP)     // 6300 storage slots

typedef float vfloat2 __attribute__((ext_vector_type(2)));

// ---------------- alpha ----------------------------------------------------
__global__ void alpha_kernel(const float* __restrict__ enc,
                             const float* __restrict__ c1_w,
                             const float* __restrict__ c1_b,
                             const float* __restrict__ f1_w,
                             const float* __restrict__ f1_b,
                             float* __restrict__ alpha) {
    int b = blockIdx.x;
    int t = threadIdx.x;
    const float4* e4 = (const float4*)(enc + (size_t)b * NC * L3);
    float s = 0.f;
    for (int j = t; j < (NC * L3) / 4; j += 256) {
        float4 v = e4[j];
        int f = j * 4;
        s += v.x * c1_w[(f + 0) / L3] * f1_w[(f + 0) % L3];
        s += v.y * c1_w[(f + 1) / L3] * f1_w[(f + 1) % L3];
        s += v.z * c1_w[(f + 2) / L3] * f1_w[(f + 2) % L3];
        s += v.w * c1_w[(f + 3) / L3] * f1_w[(f + 3) % L3];
    }
    for (int off = 32; off > 0; off >>= 1) s += __shfl_down(s, off, 64);
    __shared__ float red[4];
    int lane = t & 63, wid = t >> 6;
    if (lane == 0) red[wid] = s;
    __syncthreads();
    if (t == 0) {
        float tot = red[0] + red[1] + red[2] + red[3];
        float fwsum = 0.f;
        for (int v = 0; v < L3; ++v) fwsum += f1_w[v];
        float x = tot + c1_b[0] * fwsum + f1_b[0];
        alpha[b] = 1.f / (1.f + expf(-x));   // ALPHA_M = 1
    }
}

// ---------------- fused 3D 7^3 box blur + clip + scale (unchanged) ---------
__global__ __launch_bounds__(256) void blur3d(const float* __restrict__ in,
                                              float* __restrict__ out) {
    __shared__ float h[BHS * BHS * BHS];
    __shared__ float zb[BTS * BHS * BHS];
    float* yb = h;

    int blk = blockIdx.x;
    int c = blk / BNTILE;
    int t = blk % BNTILE;
    int tz = t / (BNT * BNT), ty = (t / BNT) % BNT, tx = t % BNT;
    int bz = tz * BTS, by = ty * BTS, bx = tx * BTS;
    const float* ib = in + (size_t)c * VOX;
    int tid = threadIdx.x;

    for (int i = tid; i < BHS * BHS * BHS; i += 256) {
        int hz = i / (BHS * BHS);
        int hy = (i / BHS) % BHS;
        int hx = i % BHS;
        int gz = bz + hz - 3, gy = by + hy - 3, gx = bx + hx - 3;
        float v = 0.f;
        if (gz >= 0 && gz < DD && gy >= 0 && gy < DD && gx >= 0 && gx < DD)
            v = ib[(gz * DD + gy) * DD + gx];
        h[i] = v;
    }
    __syncthreads();

    for (int cc = tid; cc < BHS * BHS; cc += 256) {
        float s = 0.f;
        #pragma unroll
        for (int z = 0; z < 7; ++z) s += h[z * (BHS * BHS) + cc];
        zb[cc] = s;
        for (int z = 1; z < BTS; ++z) {
            s += h[(z + 6) * (BHS * BHS) + cc] - h[(z - 1) * (BHS * BHS) + cc];
            zb[z * (BHS * BHS) + cc] = s;
        }
    }
    __syncthreads();

    for (int cc = tid; cc < BTS * BHS; cc += 256) {
        int z = cc / BHS, hx = cc % BHS;
        const float* zp = zb + z * (BHS * BHS) + hx;
        float s = 0.f;
        #pragma unroll
        for (int y = 0; y < 7; ++y) s += zp[y * BHS];
        yb[(z * BTS) * BHS + hx] = s;
        for (int y = 1; y < BTS; ++y) {
            s += zp[(y + 6) * BHS] - zp[(y - 1) * BHS];
            yb[(z * BTS + y) * BHS + hx] = s;
        }
    }
    __syncthreads();

    float* ob = out + (size_t)c * VOX;
    for (int i = tid; i < BTS * BTS * BTS; i += 256) {
        int z = i >> 8, y = (i >> 4) & 15, x = i & 15;
        const float* yp = yb + (z * BTS + y) * BHS;
        float s = yp[x] + yp[x + 1] + yp[x + 2] + yp[x + 3]
                + yp[x + 4] + yp[x + 5] + yp[x + 6];
        s *= (1.0f / 343.0f);
        s = fminf(fmaxf(s, -0.01f), 0.01f);
        ob[((bz + z) * DD + (by + y)) * DD + (bx + x)] = s * 96.0f;
    }
}

// ---------------- tiled trilinear sampling, (8,16,32) tile, x-pairs --------
__global__ __launch_bounds__(256) void sample_tile(
        const float* __restrict__ orig,
        const float* __restrict__ mask,
        const float* __restrict__ field,
        const float* __restrict__ alpha,
        float* __restrict__ out) {
    __shared__ __half2 tile[HLDS];

    int blk = blockIdx.x;
    int b = blk / STILE;
    int r = blk % STILE;
    int o = r & 7;         // octant -> XCD (216 % 8 == 0)
    int l = r >> 3;        // 0..26 within octant
    int gzg = o >> 1;      // z-group 0..3
    int gyg = o & 1;       // y-group 0..1
    int lz3 = l / 9, ly3 = (l / 3) % 3, lx3 = l % 3;
    int tz = gzg * 3 + lz3;
    int ty = gyg * 3 + ly3;
    int tx = lx3;
    int bz = tz * TZ, by = ty * TY, bx = tx * TX;

    const float* ob = orig + (size_t)b * VOX;
    const float* mb = mask + (size_t)b * VOX;
    int tid = threadIdx.x;

    // stage (orig,mask) halo as half2
    for (int i = tid; i < HN; i += 256) {
        int hz = i / (HYS * HXS);
        int rr = i - hz * (HYS * HXS);
        int hy = rr / HXS;
        int hx = rr - hy * HXS;
        int gz = min(max(bz + hz - 1, 0), DD - 1);
        int gy = min(max(by + hy - 1, 0), DD - 1);
        int gx = min(max(bx + hx - 1, 0), DD - 1);
        int g = (gz * DD + gy) * DD + gx;
        tile[(hz * HYS + hy) * HXP + hx] = __floats2half2_rn(ob[g], mb[g]);
    }
    float a = alpha[b];
    __syncthreads();

    const float2* fz2 = (const float2*)field;
    const float2* fy2 = (const float2*)(field + VOX);
    const float2* fx2 = (const float2*)(field + 2 * VOX);
    vfloat2* oD = (vfloat2*)(out);
    vfloat2* oM = (vfloat2*)(out + (size_t)NB * VOX);

    int ly = tid >> 4;          // 0..15
    int lxp = tid & 15;         // x-pair index 0..15
    int gy = by + ly;
    int gx0 = bx + 2 * lxp;

    #pragma unroll 2
    for (int it = 0; it < TZ; ++it) {
        int gz = bz + it;
        int voxel = (gz * DD + gy) * DD + gx0;   // even
        int vp = voxel >> 1;

        float2 dzp = fz2[vp];
        float2 dyp = fy2[vp];
        float2 dxp = fx2[vp];

        float rD[2], rM[2];
        #pragma unroll
        for (int k = 0; k < 2; ++k) {
            int gx = gx0 + k;
            float cz = (float)gz + a * (k ? dzp.y : dzp.x);
            float cy = (float)gy + a * (k ? dyp.y : dyp.x);
            float cx = (float)gx + a * (k ? dxp.y : dxp.x);
            cz = fminf(fmaxf(cz, 0.f), (float)(DD - 1));
            cy = fminf(fmaxf(cy, 0.f), (float)(DD - 1));
            cx = fminf(fmaxf(cx, 0.f), (float)(DD - 1));

            int z0 = (int)floorf(cz); int z1 = min(z0 + 1, DD - 1);
            int y0 = (int)floorf(cy); int y1 = min(y0 + 1, DD - 1);
            int x0 = (int)floorf(cx); int x1 = min(x0 + 1, DD - 1);
            float fzf = cz - (float)z0;
            float fyf = cy - (float)y0;
            float fxf = cx - (float)x0;
            float qz = 1.f - fzf, qy = 1.f - fyf, qx = 1.f - fxf;

            int hz0 = z0 - bz + 1, hz1 = z1 - bz + 1;
            int hy0 = y0 - by + 1, hy1 = y1 - by + 1;
            int hx0 = x0 - bx + 1, hx1 = x1 - bx + 1;

            int r00 = (hz0 * HYS + hy0) * HXP;
            int r01 = (hz0 * HYS + hy1) * HXP;
            int r10 = (hz1 * HYS + hy0) * HXP;
            int r11 = (hz1 * HYS + hy1) * HXP;

            float2 v000 = __half22float2(tile[r00 + hx0]);
            float2 v001 = __half22float2(tile[r00 + hx1]);
            float2 v010 = __half22float2(tile[r01 + hx0]);
            float2 v011 = __half22float2(tile[r01 + hx1]);
            float2 v100 = __half22float2(tile[r10 + hx0]);
            float2 v101 = __half22float2(tile[r10 + hx1]);
            float2 v110 = __half22float2(tile[r11 + hx0]);
            float2 v111 = __half22float2(tile[r11 + hx1]);

            float c00 = v000.x * qx + v001.x * fxf;
            float c01 = v010.x * qx + v011.x * fxf;
            float c10 = v100.x * qx + v101.x * fxf;
            float c11 = v110.x * qx + v111.x * fxf;
            float m00 = v000.y * qx + v001.y * fxf;
            float m01 = v010.y * qx + v011.y * fxf;
            float m10 = v100.y * qx + v101.y * fxf;
            float m11 = v110.y * qx + v111.y * fxf;

            float c0 = c00 * qy + c01 * fyf;
            float c1 = c10 * qy + c11 * fyf;
            float m0 = m00 * qy + m01 * fyf;
            float m1 = m10 * qy + m11 * fyf;

            rD[k] = c0 * qz + c1 * fzf;
            rM[k] = m0 * qz + m1 * fzf;
        }
        size_t base = (size_t)b * (VOX / 2) + vp;
        vfloat2 vD = {rD[0], rD[1]};
        vfloat2 vM = {rM[0], rM[1]};
        __builtin_nontemporal_store(vD, &oD[base]);
        __builtin_nontemporal_store(vM, &oM[base]);
    }
}

extern "C" void kernel_launch(void* const* d_in, const int* in_sizes, int n_in,
                              void* d_out, int out_size, void* d_ws, size_t ws_size,
                              hipStream_t stream) {
    const float* enc   = (const float*)d_in[0];
    const float* orig  = (const float*)d_in[1];
    const float* mask  = (const float*)d_in[2];
    const float* c1_w  = (const float*)d_in[3];
    const float* c1_b  = (const float*)d_in[4];
    const float* f1_w  = (const float*)d_in[5];
    const float* f1_b  = (const float*)d_in[6];
    const float* offs  = (const float*)d_in[7];
    float* out = (float*)d_out;

    float* ws = (float*)d_ws;
    float* alpha = ws;                 // 8 floats
    float* fieldB = ws + 16;           // 3*VOX floats (final blurred field)

    alpha_kernel<<<NB, 256, 0, stream>>>(enc, c1_w, c1_b, f1_w, f1_b, alpha);
    blur3d<<<3 * BNTILE, 256, 0, stream>>>(offs, fieldB);
    sample_tile<<<NB * STILE, 256, 0, stream>>>(orig, mask, fieldB, alpha, out);
}